// Round 3
// baseline (176.974 us; speedup 1.0000x reference)
//
#include <hip/hip_runtime.h>
#include <hip/hip_bf16.h>

#define N_NODES 50000
#define N_EDGES 800000
#define IN_DIM  256
#define OUT_DIM 128

#define NBINS        256      // bins of 196 rows: 256*196 = 50176 >= 50000
#define ROWS_PER_BIN 196
#define BIN_CAP      3600     // mean 3125 + 8.5 sigma
#define EPB          2048     // edges per bin-block
#define NB_BIN       391      // ceil(800000/2048)
#define NB_GEMM      782      // ceil(3125 tiles / 4 waves per block)
#define CUR_STRIDE   32       // R11: one 128B cacheline per bin cursor (no false sharing)

typedef __bf16 bf16x8 __attribute__((ext_vector_type(8)));
typedef float  f32x4  __attribute__((ext_vector_type(4)));

// bin = floor(row/196) via magic: (r*85599)>>24, exact for r < 50176 (verified R5-R7)
__device__ __forceinline__ unsigned bin_of(unsigned r) { return (r * 85599u) >> 24; }
__device__ __forceinline__ float blo(unsigned u) { return __uint_as_float(u << 16); }
__device__ __forceinline__ float bhi(unsigned u) { return __uint_as_float(u & 0xffff0000u); }

// ---------------------------------------------------------------------------
// ws layout (bytes)
// ---------------------------------------------------------------------------
#define WT_OFF   0                      // 64 KB    : Wt bf16 [128][256]
#define SUP_OFF  65536                  // 12.8 MB  : support u32 [50000][64] planar-pair
#define BIN_OFF  12865536               // 7.37 MB  : binbuf int2[256*3600]
#define CUR_OFF  20238336               // 32 KB    : bin_cursor int[256*CUR_STRIDE]

// ---------------------------------------------------------------------------
// prep: Wt transpose+bf16; bin_cursor[b*CUR_STRIDE] = b*BIN_CAP
// ---------------------------------------------------------------------------
__global__ void k_prep(const float* __restrict__ W, __bf16* __restrict__ Wt,
                       int* __restrict__ bin_cursor) {
    int t = blockIdx.x * 256 + threadIdx.x;
    if (t < 32768) { int n = t >> 8, k = t & 255; Wt[t] = (__bf16)W[k * OUT_DIM + n]; }
    if (t < NBINS) bin_cursor[t * CUR_STRIDE] = t * BIN_CAP;
}

// ---------------------------------------------------------------------------
// Fused kernel.
//  blocks [0, NB_BIN): R10 lean binning, R11: cacheline-padded global cursors
//    (one atomicAdd per (block,bin), each bin cursor in its own 128B line).
//  blocks [NB_BIN, ..): GEMM, R11: full A-tile prefetch -- all 16 dwordx4
//    x-loads issued before any MFMA (16 HBM loads in flight per wave),
//    progressive bf16 conversion.  Fragment roles + planar-pair epilogue
//    identical to the verified R7 mapping.
// ---------------------------------------------------------------------------
__global__ __launch_bounds__(256) void k_fused(const float* __restrict__ x,
                                               const __bf16* __restrict__ Wt,
                                               unsigned* __restrict__ sup32,
                                               const int* __restrict__ rows,
                                               const int* __restrict__ cols,
                                               const float* __restrict__ vals,
                                               int* __restrict__ bin_cursor,
                                               int2* __restrict__ binbuf) {
    __shared__ int s_cur[NBINS];    // per-block per-bin count / rank cursor
    __shared__ int s_base[NBINS];   // global base per bin for this block
    int t = threadIdx.x;

    if (blockIdx.x < NB_BIN) {
        // ---------------- lean bin path (R10 + padded cursors) ----------------
        long e0 = (long)blockIdx.x * EPB;
        s_cur[t] = 0;
        __syncthreads();

        int2 rec[8];
        int  lrank[8];
        bool full = (e0 + EPB <= N_EDGES);   // true for 390 of 391 blocks

        if (full) {
#pragma unroll
            for (int k = 0; k < 8; ++k) {
                long e = e0 + k * 256 + t;
                unsigned r = (unsigned)rows[e];
                unsigned c = (unsigned)cols[e];
                float    w = vals[e];
                rec[k]   = make_int2((int)((r << 16) | c), __float_as_int(w));
                lrank[k] = atomicAdd(&s_cur[bin_of(r)], 1);
            }
        } else {
#pragma unroll
            for (int k = 0; k < 8; ++k) {
                long e = e0 + k * 256 + t;
                lrank[k] = -1;
                if (e < N_EDGES) {
                    unsigned r = (unsigned)rows[e];
                    unsigned c = (unsigned)cols[e];
                    float    w = vals[e];
                    rec[k]   = make_int2((int)((r << 16) | c), __float_as_int(w));
                    lrank[k] = atomicAdd(&s_cur[bin_of(r)], 1);
                }
            }
        }
        __syncthreads();

        s_base[t] = atomicAdd(&bin_cursor[t * CUR_STRIDE], s_cur[t]);
        __syncthreads();

        if (full) {
#pragma unroll
            for (int k = 0; k < 8; ++k) {
                unsigned bn = bin_of(((unsigned)rec[k].x) >> 16);
                int dst = s_base[bn] + lrank[k];
                if (dst < (int)(bn + 1) * BIN_CAP)
                    binbuf[dst] = rec[k];
            }
        } else {
#pragma unroll
            for (int k = 0; k < 8; ++k) {
                if (lrank[k] >= 0) {
                    unsigned bn = bin_of(((unsigned)rec[k].x) >> 16);
                    int dst = s_base[bn] + lrank[k];
                    if (dst < (int)(bn + 1) * BIN_CAP)
                        binbuf[dst] = rec[k];
                }
            }
        }
    } else {
        // ---------------- gemm path: 1 wave = 1 tile of 16 rows ----------------
        int  gb   = blockIdx.x - NB_BIN;             // 0..781
        int  wave = t >> 6;
        int  lane = t & 63;
        int  tile = gb * 4 + wave;                   // 0..3127
        if (tile >= 3125) return;                    // no barriers below: safe
        int  m    = lane & 15;
        int  quad = lane >> 4;

        // A: lane (m,quad) streams row tile*16+m, bytes quad*32 + ks*128.
        // 3125*16 == 50000 -> every row in-bounds, no guard.
        const float*  aprow = x  + ((long)tile * 16 + m) * IN_DIM + quad * 8;
        // B: Wt[n-row][k] with n = nt*16 + m, k = quad*8 + ks*32 (verified R7 roles)
        const __bf16* wpB   = Wt + m * IN_DIM + quad * 8;

        // R11: issue ALL 16 A-loads before any MFMA (full-tile MLP).
        float4 fa[16];
#pragma unroll
        for (int ks = 0; ks < 8; ++ks) {
            fa[2 * ks]     = *(const float4*)(aprow + ks * 32);
            fa[2 * ks + 1] = *(const float4*)(aprow + ks * 32 + 4);
        }

        f32x4 acc[8];
#pragma unroll
        for (int n = 0; n < 8; ++n) acc[n] = (f32x4){0, 0, 0, 0};

#pragma unroll
        for (int ks = 0; ks < 8; ++ks) {
            float4 f0 = fa[2 * ks];
            float4 f1 = fa[2 * ks + 1];
            __bf16 c0 = (__bf16)f0.x, c1 = (__bf16)f0.y;
            __bf16 c2 = (__bf16)f0.z, c3 = (__bf16)f0.w;
            __bf16 c4 = (__bf16)f1.x, c5 = (__bf16)f1.y;
            __bf16 c6 = (__bf16)f1.z, c7 = (__bf16)f1.w;
            bf16x8 af = (bf16x8){c0, c1, c2, c3, c4, c5, c6, c7};
#pragma unroll
            for (int n = 0; n < 8; ++n) {
                bf16x8 bfr = *(const bf16x8*)(wpB + n * 16 * IN_DIM + ks * 32);
                acc[n] = __builtin_amdgcn_mfma_f32_16x16x32_bf16(af, bfr, acc[n], 0, 0, 0);
            }
        }

        // planar-pair epilogue (verified R7): word j = n*16+m = ch j | ch j+64
        unsigned* op = sup32 + (long)tile * 16 * 64;
#pragma unroll
        for (int r = 0; r < 4; ++r) {
#pragma unroll
            for (int n = 0; n < 4; ++n) {
                __bf16 lo = (__bf16)acc[n][r], hi = (__bf16)acc[n + 4][r];
                unsigned w = (unsigned)*(unsigned short*)&lo |
                             ((unsigned)*(unsigned short*)&hi << 16);
                op[(quad * 4 + r) * 64 + n * 16 + m] = w;
            }
        }
    }
}

// ---------------------------------------------------------------------------
// k_sg: fused per-bin counting sort + gather (R9 predicated gather, verified).
// ---------------------------------------------------------------------------
__global__ __launch_bounds__(1024) void k_sg(const int* __restrict__ bin_cursor,
                                             const int2* __restrict__ binbuf,
                                             const unsigned* __restrict__ sup,
                                             const float* __restrict__ bias,
                                             float* __restrict__ out) {
    __shared__ int2 stage[BIN_CAP];                // 28.8 KB
    __shared__ int2 sorted_[BIN_CAP];              // 28.8 KB
    __shared__ int  cnt[256], off[256], cur[256], s[256];
    int b = blockIdx.x, t = threadIdx.x;
    int row0 = b * ROWS_PER_BIN;

    int n = bin_cursor[b * CUR_STRIDE] - b * BIN_CAP;
    n = n < 0 ? 0 : (n > BIN_CAP ? BIN_CAP : n);
    const int2* seg = binbuf + (long)b * BIN_CAP;

    if (t < 256) cnt[t] = 0;
    __syncthreads();

    for (int i = t; i < n; i += 1024) {
        int2 rec = seg[i];
        stage[i] = rec;
        atomicAdd(&cnt[(int)(((unsigned)rec.x) >> 16) - row0], 1);
    }
    __syncthreads();

    int v = 0;
    if (t < 256) { v = cnt[t]; s[t] = v; }
    __syncthreads();
#pragma unroll
    for (int o = 1; o < 256; o <<= 1) {
        int xv = 0;
        if (t < 256 && t >= o) xv = s[t - o];
        __syncthreads();
        if (t < 256) s[t] += xv;
        __syncthreads();
    }
    if (t < 256) { off[t] = s[t] - v; cur[t] = 0; }
    __syncthreads();

    for (int i = t; i < n; i += 1024) {
        int2 rec = stage[i];
        int rl = (int)(((unsigned)rec.x) >> 16) - row0;
        sorted_[off[rl] + atomicAdd(&cur[rl], 1)] = rec;
    }
    __syncthreads();

    int wave = t >> 6, lane = t & 63;
    float bb0 = bias[lane], bb1 = bias[64 + lane];

    for (int rl = wave; rl < ROWS_PER_BIN; rl += 16) {
        int row = row0 + rl;
        if (row >= N_NODES) continue;
        int st = off[rl], nd = cnt[rl];
        float a0 = 0.f, a1 = 0.f;
        for (int i = 0; i < nd; i += 8) {
            int2 e[8]; unsigned u[8]; float vv[8];
#pragma unroll
            for (int j = 0; j < 8; ++j) {
                int ok = (i + j) < nd;
                e[j]  = sorted_[ok ? st + i + j : st];
                vv[j] = ok ? __int_as_float(e[j].y) : 0.f;
            }
#pragma unroll
            for (int j = 0; j < 8; ++j)
                u[j] = sup[(long)(((unsigned)e[j].x) & 0xffffu) * 64 + lane];
#pragma unroll
            for (int j = 0; j < 8; ++j) {
                a0 += vv[j] * blo(u[j]);
                a1 += vv[j] * bhi(u[j]);
            }
        }
        out[(long)row * 128 + lane]      = a0 + bb0;
        out[(long)row * 128 + 64 + lane] = a1 + bb1;
    }
}

// ---------------------------------------------------------------------------
extern "C" void kernel_launch(void* const* d_in, const int* in_sizes, int n_in,
                              void* d_out, int out_size, void* d_ws, size_t ws_size,
                              hipStream_t stream) {
    const int*   adj_rows = (const int*)  d_in[0];
    const int*   adj_cols = (const int*)  d_in[1];
    const float* adj_vals = (const float*)d_in[2];
    const float* x        = (const float*)d_in[3];
    const float* W        = (const float*)d_in[4];
    const float* b        = (const float*)d_in[5];
    float* out = (float*)d_out;

    char* ws = (char*)d_ws;
    __bf16*   Wt         = (__bf16*)  (ws + WT_OFF);
    unsigned* sup32      = (unsigned*)(ws + SUP_OFF);
    int2*     binbuf     = (int2*)    (ws + BIN_OFF);
    int*      bin_cursor = (int*)     (ws + CUR_OFF);

    k_prep <<<128, 256, 0, stream>>>(W, Wt, bin_cursor);
    k_fused<<<NB_BIN + NB_GEMM, 256, 0, stream>>>(x, Wt, sup32,
                                                  adj_rows, adj_cols, adj_vals,
                                                  bin_cursor, binbuf);
    k_sg   <<<NBINS, 1024, 0, stream>>>(bin_cursor, binbuf, sup32, b, out);
}

// Round 4
// 160.541 us; speedup vs baseline: 1.1024x; 1.1024x over previous
//
#include <hip/hip_runtime.h>
#include <hip/hip_bf16.h>

#define N_NODES 50000
#define N_EDGES 800000
#define IN_DIM  256
#define OUT_DIM 128

#define NBINS        256      // bins of 196 rows: 256*196 = 50176 >= 50000
#define ROWS_PER_BIN 196
#define BIN_CAP      3600     // mean 3125 + 8.5 sigma
#define EPB          2048     // edges per bin-block
#define NB_BIN       391      // ceil(800000/2048)
#define NB_GEMM      782      // ceil(3128 waves / 4 waves per block), 1 wave = 1 tile
#define CUR_STRIDE   32       // one 128B cacheline per bin cursor

typedef __bf16 bf16x8 __attribute__((ext_vector_type(8)));
typedef float  f32x4  __attribute__((ext_vector_type(4)));

// bin = floor(row/196) via magic: (r*85599)>>24, exact for r < 50176 (verified R5-R7)
__device__ __forceinline__ unsigned bin_of(unsigned r) { return (r * 85599u) >> 24; }
__device__ __forceinline__ float blo(unsigned u) { return __uint_as_float(u << 16); }
__device__ __forceinline__ float bhi(unsigned u) { return __uint_as_float(u & 0xffff0000u); }

// ---------------------------------------------------------------------------
// ws layout (bytes)
// ---------------------------------------------------------------------------
#define WF_OFF   0                      // 64 KB    : Wf bf16 frag-order [4096 slots][8]
#define SUP_OFF  65536                  // 12.8 MB  : support u32 [50000][64] planar-pair
#define BIN_OFF  12865536               // 7.37 MB  : binbuf int2[256*3600]
#define CUR_OFF  20238336               // 32 KB    : bin_cursor int[256*CUR_STRIDE]

// ---------------------------------------------------------------------------
// prep (R12): Wf = W in MFMA B-fragment order.
// Slot s (16B = 8 halfs): n = s>>9, ks = (s>>6)&7, lane = s&63, m = lane&15,
// quad = (lane>>4); half j holds Wt[n*16+m][quad*8 + ks*32 + j]
//                         = W[(quad*8+ks*32+j)*OUT_DIM + (n*16+m)].
// In k_gemm, lane reads slot (n*8+ks)*64+lane -> exactly its B-frag,
// consecutive lanes -> consecutive 16B slots -> zero-conflict ds_read_b128.
// ---------------------------------------------------------------------------
__global__ void k_prep(const float* __restrict__ W, __bf16* __restrict__ Wf,
                       int* __restrict__ bin_cursor) {
    int t = blockIdx.x * 256 + threadIdx.x;
    if (t < 32768) {
        int s = t >> 3, j = t & 7;
        int nrow = ((s >> 9) << 4) | (s & 15);                 // n*16 + m
        int k    = (((s >> 4) & 3) << 3) | (((s >> 6) & 7) << 5) | j;
        Wf[t] = (__bf16)W[k * OUT_DIM + nrow];
    }
    if (t < NBINS) bin_cursor[t * CUR_STRIDE] = t * BIN_CAP;
}

// ---------------------------------------------------------------------------
// k_bin (R12: standalone; body = verified R10 lean binning).
// One pass over edges held in regs; per-edge LDS rank atomic; per-bin global
// base atomic (cacheline-padded cursors); direct scattered write.
// ---------------------------------------------------------------------------
__global__ __launch_bounds__(256) void k_bin(const int* __restrict__ rows,
                                             const int* __restrict__ cols,
                                             const float* __restrict__ vals,
                                             int* __restrict__ bin_cursor,
                                             int2* __restrict__ binbuf) {
    __shared__ int s_cur[NBINS];
    __shared__ int s_base[NBINS];
    int t = threadIdx.x;

    long e0 = (long)blockIdx.x * EPB;
    s_cur[t] = 0;
    __syncthreads();

    int2 rec[8];
    int  lrank[8];
    bool full = (e0 + EPB <= N_EDGES);   // true for 390 of 391 blocks

    if (full) {
#pragma unroll
        for (int k = 0; k < 8; ++k) {
            long e = e0 + k * 256 + t;
            unsigned r = (unsigned)rows[e];
            unsigned c = (unsigned)cols[e];
            float    w = vals[e];
            rec[k]   = make_int2((int)((r << 16) | c), __float_as_int(w));
            lrank[k] = atomicAdd(&s_cur[bin_of(r)], 1);
        }
    } else {
#pragma unroll
        for (int k = 0; k < 8; ++k) {
            long e = e0 + k * 256 + t;
            lrank[k] = -1;
            if (e < N_EDGES) {
                unsigned r = (unsigned)rows[e];
                unsigned c = (unsigned)cols[e];
                float    w = vals[e];
                rec[k]   = make_int2((int)((r << 16) | c), __float_as_int(w));
                lrank[k] = atomicAdd(&s_cur[bin_of(r)], 1);
            }
        }
    }
    __syncthreads();

    s_base[t] = atomicAdd(&bin_cursor[t * CUR_STRIDE], s_cur[t]);
    __syncthreads();

    if (full) {
#pragma unroll
        for (int k = 0; k < 8; ++k) {
            unsigned bn = bin_of(((unsigned)rec[k].x) >> 16);
            int dst = s_base[bn] + lrank[k];
            if (dst < (int)(bn + 1) * BIN_CAP)
                binbuf[dst] = rec[k];
        }
    } else {
#pragma unroll
        for (int k = 0; k < 8; ++k) {
            if (lrank[k] >= 0) {
                unsigned bn = bin_of(((unsigned)rec[k].x) >> 16);
                int dst = s_base[bn] + lrank[k];
                if (dst < (int)(bn + 1) * BIN_CAP)
                    binbuf[dst] = rec[k];
            }
        }
    }
}

// ---------------------------------------------------------------------------
// k_gemm (R12): support = x @ W with B RESIDENT IN LDS.
//  - whole block copies Wf (64 KB, frag-order) -> LDS, fully coalesced.
//  - 1 wave = 1 tile of 16 rows; A: 16 dwordx4 global loads, all issued then
//    converted to bf16 before the MFMA loop (launch_bounds(256,2) lifts the
//    VGPR clamp that nullified R11's prefetch: VGPR stayed 64 there).
//  - B: zero-conflict stride-1 ds_read_b128 from the frag-order tile.
//  Fragment roles + planar-pair epilogue identical to verified R7 mapping.
// ---------------------------------------------------------------------------
__global__ __launch_bounds__(256, 2) void k_gemm(const float* __restrict__ x,
                                                 const __bf16* __restrict__ Wf,
                                                 unsigned* __restrict__ sup32) {
    __shared__ uint4 sB[4096];                     // 64 KB: all of Wf
    int t = threadIdx.x;

    const uint4* wf4 = (const uint4*)Wf;
#pragma unroll
    for (int r = 0; r < 16; ++r) sB[r * 256 + t] = wf4[r * 256 + t];
    __syncthreads();

    int  wave = t >> 6;
    int  lane = t & 63;
    long tile = (long)blockIdx.x * 4 + wave;       // 0..3127
    if (tile >= 3125) return;                      // after the barrier: safe
    int  m    = lane & 15;
    int  quad = lane >> 4;

    // A: lane (m,quad) streams row tile*16+m, bytes quad*32 + ks*128.
    // 3125*16 == 50000 -> every row in-bounds, no guard.
    const float* aprow = x + (tile * 16 + m) * IN_DIM + quad * 8;

    // issue all 16 A-loads, then convert to bf16 fragments (frees fa regs)
    float4 fa[16];
#pragma unroll
    for (int ks = 0; ks < 8; ++ks) {
        fa[2 * ks]     = *(const float4*)(aprow + ks * 32);
        fa[2 * ks + 1] = *(const float4*)(aprow + ks * 32 + 4);
    }
    bf16x8 ab[8];
#pragma unroll
    for (int ks = 0; ks < 8; ++ks) {
        float4 f0 = fa[2 * ks];
        float4 f1 = fa[2 * ks + 1];
        ab[ks] = (bf16x8){(__bf16)f0.x, (__bf16)f0.y, (__bf16)f0.z, (__bf16)f0.w,
                          (__bf16)f1.x, (__bf16)f1.y, (__bf16)f1.z, (__bf16)f1.w};
    }

    f32x4 acc[8];
#pragma unroll
    for (int n = 0; n < 8; ++n) acc[n] = (f32x4){0, 0, 0, 0};

    const __bf16* sbh = (const __bf16*)sB;
#pragma unroll
    for (int ks = 0; ks < 8; ++ks) {
#pragma unroll
        for (int n = 0; n < 8; ++n) {
            // slot (n*8+ks)*64 + lane : consecutive lanes -> consecutive 16B
            bf16x8 bfr = *(const bf16x8*)(sbh + (((n * 8 + ks) * 64 + lane) << 3));
            acc[n] = __builtin_amdgcn_mfma_f32_16x16x32_bf16(ab[ks], bfr, acc[n], 0, 0, 0);
        }
    }

    // planar-pair epilogue (verified R7): word j = n*16+m = ch j | ch j+64
    unsigned* op = sup32 + (long)tile * 16 * 64;
#pragma unroll
    for (int r = 0; r < 4; ++r) {
#pragma unroll
        for (int n = 0; n < 4; ++n) {
            __bf16 lo = (__bf16)acc[n][r], hi = (__bf16)acc[n + 4][r];
            unsigned w = (unsigned)*(unsigned short*)&lo |
                         ((unsigned)*(unsigned short*)&hi << 16);
            op[(quad * 4 + r) * 64 + n * 16 + m] = w;
        }
    }
}

// ---------------------------------------------------------------------------
// k_sg: fused per-bin counting sort + gather (verified; unchanged this round).
// ---------------------------------------------------------------------------
__global__ __launch_bounds__(1024) void k_sg(const int* __restrict__ bin_cursor,
                                             const int2* __restrict__ binbuf,
                                             const unsigned* __restrict__ sup,
                                             const float* __restrict__ bias,
                                             float* __restrict__ out) {
    __shared__ int2 stage[BIN_CAP];                // 28.8 KB
    __shared__ int2 sorted_[BIN_CAP];              // 28.8 KB
    __shared__ int  cnt[256], off[256], cur[256], s[256];
    int b = blockIdx.x, t = threadIdx.x;
    int row0 = b * ROWS_PER_BIN;

    int n = bin_cursor[b * CUR_STRIDE] - b * BIN_CAP;
    n = n < 0 ? 0 : (n > BIN_CAP ? BIN_CAP : n);
    const int2* seg = binbuf + (long)b * BIN_CAP;

    if (t < 256) cnt[t] = 0;
    __syncthreads();

    for (int i = t; i < n; i += 1024) {
        int2 rec = seg[i];
        stage[i] = rec;
        atomicAdd(&cnt[(int)(((unsigned)rec.x) >> 16) - row0], 1);
    }
    __syncthreads();

    int v = 0;
    if (t < 256) { v = cnt[t]; s[t] = v; }
    __syncthreads();
#pragma unroll
    for (int o = 1; o < 256; o <<= 1) {
        int xv = 0;
        if (t < 256 && t >= o) xv = s[t - o];
        __syncthreads();
        if (t < 256) s[t] += xv;
        __syncthreads();
    }
    if (t < 256) { off[t] = s[t] - v; cur[t] = 0; }
    __syncthreads();

    for (int i = t; i < n; i += 1024) {
        int2 rec = stage[i];
        int rl = (int)(((unsigned)rec.x) >> 16) - row0;
        sorted_[off[rl] + atomicAdd(&cur[rl], 1)] = rec;
    }
    __syncthreads();

    int wave = t >> 6, lane = t & 63;
    float bb0 = bias[lane], bb1 = bias[64 + lane];

    for (int rl = wave; rl < ROWS_PER_BIN; rl += 16) {
        int row = row0 + rl;
        if (row >= N_NODES) continue;
        int st = off[rl], nd = cnt[rl];
        float a0 = 0.f, a1 = 0.f;
        for (int i = 0; i < nd; i += 8) {
            int2 e[8]; unsigned u[8]; float vv[8];
#pragma unroll
            for (int j = 0; j < 8; ++j) {
                int ok = (i + j) < nd;
                e[j]  = sorted_[ok ? st + i + j : st];
                vv[j] = ok ? __int_as_float(e[j].y) : 0.f;
            }
#pragma unroll
            for (int j = 0; j < 8; ++j)
                u[j] = sup[(long)(((unsigned)e[j].x) & 0xffffu) * 64 + lane];
#pragma unroll
            for (int j = 0; j < 8; ++j) {
                a0 += vv[j] * blo(u[j]);
                a1 += vv[j] * bhi(u[j]);
            }
        }
        out[(long)row * 128 + lane]      = a0 + bb0;
        out[(long)row * 128 + 64 + lane] = a1 + bb1;
    }
}

// ---------------------------------------------------------------------------
extern "C" void kernel_launch(void* const* d_in, const int* in_sizes, int n_in,
                              void* d_out, int out_size, void* d_ws, size_t ws_size,
                              hipStream_t stream) {
    const int*   adj_rows = (const int*)  d_in[0];
    const int*   adj_cols = (const int*)  d_in[1];
    const float* adj_vals = (const float*)d_in[2];
    const float* x        = (const float*)d_in[3];
    const float* W        = (const float*)d_in[4];
    const float* b        = (const float*)d_in[5];
    float* out = (float*)d_out;

    char* ws = (char*)d_ws;
    __bf16*   Wf         = (__bf16*)  (ws + WF_OFF);
    unsigned* sup32      = (unsigned*)(ws + SUP_OFF);
    int2*     binbuf     = (int2*)    (ws + BIN_OFF);
    int*      bin_cursor = (int*)     (ws + CUR_OFF);

    k_prep<<<128, 256, 0, stream>>>(W, Wf, bin_cursor);
    k_bin <<<NB_BIN, 256, 0, stream>>>(adj_rows, adj_cols, adj_vals,
                                       bin_cursor, binbuf);
    k_gemm<<<NB_GEMM, 256, 0, stream>>>(x, Wf, sup32);
    k_sg  <<<NBINS, 1024, 0, stream>>>(bin_cursor, binbuf, sup32, b, out);
}